// Round 6
// baseline (281.222 us; speedup 1.0000x reference)
//
#include <hip/hip_runtime.h>
#include <math.h>

typedef __attribute__((ext_vector_type(8))) short short8;
typedef __attribute__((ext_vector_type(4))) short short4v;
typedef __attribute__((ext_vector_type(4))) float floatx4;
typedef __attribute__((ext_vector_type(16))) float floatx16;

__device__ __forceinline__ unsigned short f2bf(float f) {
  union { float f; unsigned int u; } v; v.f = f;
  unsigned int r = v.u + 0x7fffu + ((v.u >> 16) & 1u);
  return (unsigned short)(r >> 16);
}

__device__ __forceinline__ float bf2f(unsigned short h) {
  union { unsigned int u; float f; } v; v.u = ((unsigned int)h) << 16;
  return v.f;
}

__device__ __forceinline__ unsigned int pack2(unsigned short a, unsigned short b) {
  return (unsigned int)a | ((unsigned int)b << 16);
}

__device__ __forceinline__ unsigned int rbits(float f) {
  union { float f; unsigned int u; } v; v.f = f;
  return v.u + 0x8000u;  // round-half-up to bf16 when >>16
}

__device__ __forceinline__ short8 as_short8(uint4 u) {
  union { uint4 u; short8 s; } v; v.u = u; return v.s;
}

__device__ __forceinline__ float fast_exp2(float x) {
#if __has_builtin(__builtin_amdgcn_exp2f)
  return __builtin_amdgcn_exp2f(x);
#else
  return exp2f(x);
#endif
}

// async global->LDS, 16B per lane. LDS dest is wave-uniform base + lane*16.
__device__ __forceinline__ void async16(const unsigned short* gp, unsigned short* lp) {
  __builtin_amdgcn_global_load_lds(
      (__attribute__((address_space(1))) void*)(gp),
      (__attribute__((address_space(3))) void*)(lp), 16, 0, 0);
}

// ------------------------------------------------- setup: GN stats + w casts
// blocks 0..63: per-(b,g) mean/rstd. blocks 64..1087: fp32->bf16 weight cast.
__global__ void setup_kernel(const float* __restrict__ x, float* __restrict__ stats,
                             const float* __restrict__ qkv_w, unsigned short* __restrict__ wqkv,
                             const float* __restrict__ proj_w, unsigned short* __restrict__ wproj) {
  if (blockIdx.x < 64) {
    int bg = blockIdx.x;
    const float4* p = (const float4*)(x + (size_t)bg * 65536);
    float s = 0.f, ss = 0.f;
    for (int i = threadIdx.x; i < 16384; i += 256) {
      float4 v = p[i];
      s  += v.x + v.y + v.z + v.w;
      ss += v.x*v.x + v.y*v.y + v.z*v.z + v.w*v.w;
    }
    #pragma unroll
    for (int off = 32; off >= 1; off >>= 1) {
      s  += __shfl_xor(s,  off, 64);
      ss += __shfl_xor(ss, off, 64);
    }
    __shared__ float red[2][4];
    int wv = threadIdx.x >> 6;
    if ((threadIdx.x & 63) == 0) { red[0][wv] = s; red[1][wv] = ss; }
    __syncthreads();
    if (threadIdx.x == 0) {
      s  = red[0][0] + red[0][1] + red[0][2] + red[0][3];
      ss = red[1][0] + red[1][1] + red[1][2] + red[1][3];
      float mean = s * (1.f/65536.f);
      float var  = ss * (1.f/65536.f) - mean*mean;
      stats[2*bg]   = mean;
      stats[2*bg+1] = rsqrtf(var + 1e-5f);
    }
  } else {
    int i = (blockIdx.x - 64) * 256 + threadIdx.x;
    const float* s; unsigned short* d;
    if (i < 196608) { s = qkv_w; d = wqkv; }
    else { i -= 196608; s = proj_w; d = wproj; }
    float4 vv = ((const float4*)s)[i];
    uint2 o;
    o.x = pack2(f2bf(vv.x), f2bf(vv.y));
    o.y = pack2(f2bf(vv.z), f2bf(vv.w));
    ((uint2*)d)[i] = o;
  }
}

// normalize + cast bf16 + transpose to token-major h_t[B][HW][C]
__global__ void gn_apply_t(const float* __restrict__ x, const float* __restrict__ stats,
                           const float* __restrict__ gw, const float* __restrict__ gb,
                           unsigned short* __restrict__ h_t) {
  __shared__ __align__(16) unsigned short tile[64][72];
  const int b = blockIdx.z, c0 = blockIdx.y * 64, hw0 = blockIdx.x * 64;
  const int t = threadIdx.x;
  {
    const int cl = t >> 2;
    const int hs = (t & 3) * 16;
    const int c  = c0 + cl;
    const int g  = c >> 4;
    const float mean = stats[2*(b*32 + g)];
    const float rstd = stats[2*(b*32 + g) + 1];
    const float w  = gw[c] * rstd;
    const float bb = gb[c] - mean * w;
    const float4* src = (const float4*)(x + ((size_t)(b*512 + c))*4096 + hw0 + hs);
    #pragma unroll
    for (int i = 0; i < 4; i++) {
      float4 vv = src[i];
      unsigned short* d = &tile[cl][hs + i*4];
      d[0] = f2bf(vv.x*w + bb); d[1] = f2bf(vv.y*w + bb);
      d[2] = f2bf(vv.z*w + bb); d[3] = f2bf(vv.w*w + bb);
    }
  }
  __syncthreads();
  {
    const int hwl = t >> 2;
    const int cs  = (t & 3) * 16;
    uint4 w0, w1;
    w0.x = pack2(tile[cs+ 0][hwl], tile[cs+ 1][hwl]);
    w0.y = pack2(tile[cs+ 2][hwl], tile[cs+ 3][hwl]);
    w0.z = pack2(tile[cs+ 4][hwl], tile[cs+ 5][hwl]);
    w0.w = pack2(tile[cs+ 6][hwl], tile[cs+ 7][hwl]);
    w1.x = pack2(tile[cs+ 8][hwl], tile[cs+ 9][hwl]);
    w1.y = pack2(tile[cs+10][hwl], tile[cs+11][hwl]);
    w1.z = pack2(tile[cs+12][hwl], tile[cs+13][hwl]);
    w1.w = pack2(tile[cs+14][hwl], tile[cs+15][hwl]);
    unsigned short* dst = h_t + ((size_t)(b*4096 + hw0 + hwl))*512 + c0 + cs;
    *(uint4*)dst       = w0;
    *(uint4*)(dst + 8) = w1;
  }
}

// ---------------------------------------------------------------- QKV GEMM
// OUT[o][n] = sum_k A[o][k] * Bt[n][k]; epilogue scatters q_t/k_t/v.
// q pre-scaled by 0.125*log2(e). v-region uses SWAPPED mfma operands.
__global__ __launch_bounds__(256, 2)
void qkv_gemm(const unsigned short* __restrict__ A,
              const unsigned short* __restrict__ Bt,
              unsigned short* __restrict__ q_t,
              unsigned short* __restrict__ k_t,
              unsigned short* __restrict__ v_) {
  __shared__ __align__(16) unsigned short As[128*32];
  __shared__ __align__(16) unsigned short Bs[128*32];
  const int b   = blockIdx.z;
  const int n0  = blockIdx.x * 128;
  const int o0  = blockIdx.y * 128;
  const int tid = threadIdx.x;
  const int wave = tid >> 6, lane = tid & 63;
  const int wr = wave >> 1, wc = wave & 1;
  const int fm = lane & 15, fq = lane >> 4;
  const int srow = lane >> 2, scol = (lane & 3) * 8;

  const unsigned short* Ab = A + (size_t)o0 * 512;
  const unsigned short* Bb = Bt + ((size_t)b*4096 + n0) * 512;

  bool vsw[4];
  #pragma unroll
  for (int fr = 0; fr < 4; fr++) {
    const int ob = o0 + wr*64 + fr*16;
    vsw[fr] = ((ob % 192) >> 6) == 2;
  }

  floatx4 acc[4][4];
  #pragma unroll
  for (int i = 0; i < 4; i++)
    #pragma unroll
    for (int j = 0; j < 4; j++) acc[i][j] = (floatx4){0.f,0.f,0.f,0.f};

  for (int k0 = 0; k0 < 512; k0 += 32) {
    __syncthreads();
    #pragma unroll
    for (int cc = 0; cc < 2; cc++) {
      int ch = wave*2 + cc;
      async16(Ab + (size_t)(ch*16 + srow)*512 + k0 + scol, &As[ch*512]);
      async16(Bb + (size_t)(ch*16 + srow)*512 + k0 + scol, &Bs[ch*512]);
    }
    __syncthreads();
    short8 af[4], bf[4];
    #pragma unroll
    for (int f = 0; f < 4; f++) {
      af[f] = *(const short8*)&As[(wr*64 + f*16 + fm)*32 + fq*8];
      bf[f] = *(const short8*)&Bs[(wc*64 + f*16 + fm)*32 + fq*8];
    }
    #pragma unroll
    for (int fr = 0; fr < 4; fr++) {
      if (vsw[fr]) {
        #pragma unroll
        for (int fc = 0; fc < 4; fc++)
          acc[fr][fc] = __builtin_amdgcn_mfma_f32_16x16x32_bf16(bf[fc], af[fr], acc[fr][fc], 0, 0, 0);
      } else {
        #pragma unroll
        for (int fc = 0; fc < 4; fc++)
          acc[fr][fc] = __builtin_amdgcn_mfma_f32_16x16x32_bf16(af[fr], bf[fc], acc[fr][fc], 0, 0, 0);
      }
    }
  }

  #pragma unroll
  for (int fr = 0; fr < 4; fr++) {
    const int ob     = o0 + wr*64 + fr*16;
    const int head   = ob / 192;
    const int rem    = ob % 192;
    const int region = rem >> 6;             // 0=q 1=k 2=v
    const int bhh    = b*8 + head;
    #pragma unroll
    for (int fc = 0; fc < 4; fc++) {
      if (region == 0) {
        const int i = n0 + wc*64 + fc*16 + fm;
        const int dsub = (rem & 63) + fq*4;
        unsigned short t4[4];
        #pragma unroll
        for (int r = 0; r < 4; r++) t4[r] = f2bf(acc[fr][fc][r] * 0.18033688f);
        uint2 o; o.x = pack2(t4[0], t4[1]); o.y = pack2(t4[2], t4[3]);
        *(uint2*)&q_t[((size_t)bhh*4096 + i)*64 + dsub] = o;
      } else if (region == 1) {
        const int i = n0 + wc*64 + fc*16 + fm;
        const int dsub = (rem & 63) + fq*4;
        unsigned short t4[4];
        #pragma unroll
        for (int r = 0; r < 4; r++) t4[r] = f2bf(acc[fr][fc][r]);
        uint2 o; o.x = pack2(t4[0], t4[1]); o.y = pack2(t4[2], t4[3]);
        *(uint2*)&k_t[((size_t)bhh*4096 + i)*64 + dsub] = o;
      } else {
        const int dsub = (rem & 63) + fm;
        const int tok0 = n0 + wc*64 + fc*16 + fq*4;
        unsigned short t4[4];
        #pragma unroll
        for (int r = 0; r < 4; r++) t4[r] = f2bf(acc[fr][fc][r]);
        uint2 o; o.x = pack2(t4[0], t4[1]); o.y = pack2(t4[2], t4[3]);
        *(uint2*)&v_[((size_t)bhh*64 + dsub)*4096 + tok0] = o;
      }
    }
  }
}

// ---------------------------------------------------------------- proj GEMM
// 64x128 tile, grid (32,8,2)=512 blocks (2/CU). out = x + bias + acc (fp32).
__global__ __launch_bounds__(256, 2)
void proj_gemm(const unsigned short* __restrict__ A,     // wproj [512][512]
               const unsigned short* __restrict__ Bt,    // hout_t [B][4096][512]
               float* __restrict__ outp,
               const float* __restrict__ xres,
               const float* __restrict__ pbias) {
  __shared__ __align__(16) unsigned short As[64*32];
  __shared__ __align__(16) unsigned short Bs[128*32];
  const int b   = blockIdx.z;
  const int n0  = blockIdx.x * 128;
  const int o0  = blockIdx.y * 64;
  const int tid = threadIdx.x;
  const int wave = tid >> 6, lane = tid & 63;
  const int wr = wave >> 1, wc = wave & 1;   // wr: 32-row o half, wc: 64-col n half
  const int fm = lane & 15, fq = lane >> 4;
  const int srow = lane >> 2, scol = (lane & 3) * 8;

  const unsigned short* Ab = A + (size_t)o0 * 512;
  const unsigned short* Bb = Bt + ((size_t)b*4096 + n0) * 512;

  floatx4 acc[2][4];
  #pragma unroll
  for (int i = 0; i < 2; i++)
    #pragma unroll
    for (int j = 0; j < 4; j++) acc[i][j] = (floatx4){0.f,0.f,0.f,0.f};

  for (int k0 = 0; k0 < 512; k0 += 32) {
    __syncthreads();
    async16(Ab + (size_t)(wave*16 + srow)*512 + k0 + scol, &As[wave*512]);
    #pragma unroll
    for (int cc = 0; cc < 2; cc++) {
      int ch = wave*2 + cc;
      async16(Bb + (size_t)(ch*16 + srow)*512 + k0 + scol, &Bs[ch*512]);
    }
    __syncthreads();
    short8 af[2], bf[4];
    #pragma unroll
    for (int f = 0; f < 2; f++)
      af[f] = *(const short8*)&As[(wr*32 + f*16 + fm)*32 + fq*8];
    #pragma unroll
    for (int f = 0; f < 4; f++)
      bf[f] = *(const short8*)&Bs[(wc*64 + f*16 + fm)*32 + fq*8];
    #pragma unroll
    for (int fr = 0; fr < 2; fr++)
      #pragma unroll
      for (int fc = 0; fc < 4; fc++)
        acc[fr][fc] = __builtin_amdgcn_mfma_f32_16x16x32_bf16(af[fr], bf[fc], acc[fr][fc], 0, 0, 0);
  }

  #pragma unroll
  for (int fr = 0; fr < 2; fr++)
    #pragma unroll
    for (int fc = 0; fc < 4; fc++) {
      const int i = n0 + wc*64 + fc*16 + fm;
      #pragma unroll
      for (int r = 0; r < 4; r++) {
        const int o = o0 + wr*32 + fr*16 + fq*4 + r;
        const size_t idx = ((size_t)b*512 + o)*4096 + i;
        outp[idx] = xres[idx] + pbias[o] + acc[fr][fc][r];
      }
    }
}

// ---------------------------------------------------------------- attention
// q_t,k_t: [16][4096][64] bf16 (q pre-scaled by 0.125*log2e); v: [16][64][4096]
// K is streamed global->registers (A-frags are per-lane-contiguous 16B rows);
// only V goes through LDS (j-interleaved for b128 PV B-frags). Rolling 4-frag
// K prefetch one mj-phase ahead hides L2 latency. P stays in registers.
template <int SPLIT>
__global__ __launch_bounds__(256, 3)
void attn_kernel(const unsigned short* __restrict__ q_t,
                 const unsigned short* __restrict__ k_t,
                 const unsigned short* __restrict__ v_,
                 unsigned short* __restrict__ hout_t,
                 unsigned short* __restrict__ o_part,
                 float* __restrict__ l_part) {
  __shared__ __align__(16) unsigned short Vs[2][64*72];   // [d][j-interleaved], +pad

  const int bh  = blockIdx.x;
  const int q0  = blockIdx.y * 128;
  const int js  = SPLIT ? blockIdx.z : 0;
  const int nit = SPLIT ? 32 : 64;
  const int jbase = js * 2048;
  const int tid = threadIdx.x;
  const int wave = tid >> 6, lane = tid & 63;
  const int ln = lane & 31, h = lane >> 5;

  // Q B-frags (32x32x16): B[k=kc*16+h*8+t][n=ln], i = q0+wave*32+ln
  short8 qf[4];
  {
    const unsigned short* qrow = q_t + ((size_t)bh*4096 + q0 + wave*32 + ln)*64;
    #pragma unroll
    for (int kc = 0; kc < 4; kc++)
      qf[kc] = *(const short8*)(qrow + kc*16 + h*8);
  }

  const floatx16 z16 = {0.f,0.f,0.f,0.f,0.f,0.f,0.f,0.f,
                        0.f,0.f,0.f,0.f,0.f,0.f,0.f,0.f};
  floatx16 o_acc[2];
  o_acc[0] = z16; o_acc[1] = z16;
  float l = 0.f;

  const int sr = tid >> 3;          // 0..31
  const int sc = (tid & 7) * 8;     // source 8-short chunk
  const int cch = tid & 7;
  const int vpos = ((cch >> 2) * 32) + ((cch & 3) * 4);
  const unsigned short* vbase = v_ + (size_t)bh*262144;
  // per-lane K A-frag pointer: row j = (...)+ln, bytes [kc*32 + h*16, +16)
  const unsigned short* kflane = k_t + (size_t)bh*262144 + (size_t)ln*64 + h*8;

  // preload V tile 0 + K frags (it=0, mj=0)
  uint4 vr0 = *(const uint4*)&vbase[(size_t)sr*4096 + jbase + sc];
  uint4 vr1 = *(const uint4*)&vbase[(size_t)(sr+32)*4096 + jbase + sc];
  uint4 ka[4], kb[4];
  {
    const unsigned short* kp = kflane + (size_t)jbase*64;
    #pragma unroll
    for (int kc = 0; kc < 4; kc++) ka[kc] = *(const uint4*)(kp + kc*16);
  }

  for (int it = 0; it < nit; it++) {
    unsigned short* Vc = (unsigned short*)Vs[it & 1];
    *(uint2*)&Vc[sr*72 + vpos]           = *(const uint2*)&vr0;
    *(uint2*)&Vc[sr*72 + vpos + 16]      = *((const uint2*)&vr0 + 1);
    *(uint2*)&Vc[(sr+32)*72 + vpos]      = *(const uint2*)&vr1;
    *(uint2*)&Vc[(sr+32)*72 + vpos + 16] = *((const uint2*)&vr1 + 1);
    __syncthreads();

    const int jn = jbase + (((it + 1) & (nit - 1)) * 64);
    vr0 = *(const uint4*)&vbase[(size_t)sr*4096 + jn + sc];
    vr1 = *(const uint4*)&vbase[(size_t)(sr+32)*4096 + jn + sc];

    const unsigned short* kcur = kflane + ((size_t)jbase + (size_t)it*64)*64;
    const unsigned short* knxt = kflane + (size_t)jn*64;

    #pragma unroll
    for (int mj = 0; mj < 2; mj++) {
      // rolling K prefetch: during mj=0 fetch (it,mj=1); during mj=1 fetch (it+1,mj=0)
      if (mj == 0) {
        #pragma unroll
        for (int kc = 0; kc < 4; kc++) kb[kc] = *(const uint4*)(kcur + 2048 + kc*16);
      } else {
        #pragma unroll
        for (int kc = 0; kc < 4; kc++) ka[kc] = *(const uint4*)(knxt + kc*16);
      }

      // S^T = K Q^T
      floatx16 st;
      st = __builtin_amdgcn_mfma_f32_32x32x16_bf16(
          as_short8(mj == 0 ? ka[0] : kb[0]), qf[0], z16, 0, 0, 0);
      #pragma unroll
      for (int kc = 1; kc < 4; kc++)
        st = __builtin_amdgcn_mfma_f32_32x32x16_bf16(
            as_short8(mj == 0 ? ka[kc] : kb[kc]), qf[kc], st, 0, 0, 0);

      // p = exp2(s'), accumulate l, pack to bf16 pairs
      unsigned pk[8];
      #pragma unroll
      for (int rp = 0; rp < 8; rp++) {
        float p0 = fast_exp2(st[2*rp]);
        float p1 = fast_exp2(st[2*rp + 1]);
        l += p0 + p1;
        pk[rp] = __builtin_amdgcn_perm(rbits(p1), rbits(p0), 0x07060302u);
      }

      // O += P V via 32x32x8 (V b128 covers 2 subtiles, interleaved layout)
      #pragma unroll
      for (int t2 = 0; t2 < 2; t2++) {
        union { unsigned u[2]; short4v s; } a0, a1;
        a0.u[0] = pk[4*t2];     a0.u[1] = pk[4*t2 + 1];
        a1.u[0] = pk[4*t2 + 2]; a1.u[1] = pk[4*t2 + 3];
        #pragma unroll
        for (int dn = 0; dn < 2; dn++) {
          short8 vv = *(const short8*)&Vc[(dn*32 + ln)*72 + mj*32 + h*16 + t2*8];
          short4v vlo = __builtin_shufflevector(vv, vv, 0, 1, 2, 3);
          short4v vhi = __builtin_shufflevector(vv, vv, 4, 5, 6, 7);
          o_acc[dn] = __builtin_amdgcn_mfma_f32_32x32x8bf16_1k(a0.s, vlo, o_acc[dn], 0, 0, 0);
          o_acc[dn] = __builtin_amdgcn_mfma_f32_32x32x8bf16_1k(a1.s, vhi, o_acc[dn], 0, 0, 0);
        }
      }
    }
  }

  // column sums complete within lane pairs (h=0/1)
  l += __shfl_xor(l, 32, 64);

  if (SPLIT) {
    unsigned short* op = o_part + (((size_t)(js*16 + bh)*4096 + q0 + wave*32) * 64);
    #pragma unroll
    for (int r = 0; r < 16; r++) {
      const int il = (r & 3) + 8*(r >> 2) + 4*h;
      op[(size_t)il*64 + ln]      = f2bf(o_acc[0][r]);
      op[(size_t)il*64 + 32 + ln] = f2bf(o_acc[1][r]);
    }
    if (lane < 32)
      l_part[(size_t)(js*16 + bh)*4096 + q0 + wave*32 + lane] = l;
  } else {
    const float linv = 1.f / l;
    const int bb = bh >> 3;
    const int cb = (bh & 7) * 64;
    #pragma unroll
    for (int r = 0; r < 16; r++) {
      const int il = (r & 3) + 8*(r >> 2) + 4*h;
      const float inv = __shfl(linv, il, 64);
      const int i = q0 + wave*32 + il;
      unsigned short* dst = &hout_t[((size_t)bb*4096 + i)*512 + cb + ln];
      dst[0]  = f2bf(o_acc[0][r] * inv);
      dst[32] = f2bf(o_acc[1][r] * inv);
    }
  }
}

// combine: hout = (O0+O1)/(l0+l1), bf16 token-major
__global__ void attn_combine(const unsigned short* __restrict__ o_part,
                             const float* __restrict__ l_part,
                             unsigned short* __restrict__ hout_t) {
  const int bh = blockIdx.x;
  const int i0 = blockIdx.y * 64;
  const int t  = threadIdx.x;
  const int d4 = (t & 15) * 4;
  const int il = t >> 4;
  const int bb = bh >> 3;
  const int cb = (bh & 7) * 64;
  const size_t JS = (size_t)16 * 4096 * 64;   // js stride in o_part
  #pragma unroll
  for (int p = 0; p < 4; p++) {
    const int i = i0 + p*16 + il;
    const size_t ob = ((size_t)bh*4096 + i)*64 + d4;
    uint2 a = *(const uint2*)&o_part[ob];
    uint2 b = *(const uint2*)&o_part[ob + JS];
    const size_t lb = (size_t)bh*4096 + i;
    const float inv = 1.f / (l_part[lb] + l_part[lb + 65536]);
    float o0 = (bf2f((unsigned short)(a.x & 0xffff)) + bf2f((unsigned short)(b.x & 0xffff))) * inv;
    float o1 = (bf2f((unsigned short)(a.x >> 16))    + bf2f((unsigned short)(b.x >> 16)))    * inv;
    float o2 = (bf2f((unsigned short)(a.y & 0xffff)) + bf2f((unsigned short)(b.y & 0xffff))) * inv;
    float o3 = (bf2f((unsigned short)(a.y >> 16))    + bf2f((unsigned short)(b.y >> 16)))    * inv;
    uint2 w;
    w.x = pack2(f2bf(o0), f2bf(o1));
    w.y = pack2(f2bf(o2), f2bf(o3));
    *(uint2*)&hout_t[((size_t)bb*4096 + i)*512 + cb + d4] = w;
  }
}

// ---------------------------------------------------------------- launcher
extern "C" void kernel_launch(void* const* d_in, const int* in_sizes, int n_in,
                              void* d_out, int out_size, void* d_ws, size_t ws_size,
                              hipStream_t stream) {
  (void)in_sizes; (void)n_in; (void)out_size;
  const float* x      = (const float*)d_in[0];
  const float* qkv_w  = (const float*)d_in[1];
  const float* proj_w = (const float*)d_in[2];
  const float* proj_b = (const float*)d_in[3];
  const float* gn_w   = (const float*)d_in[4];
  const float* gn_b   = (const float*)d_in[5];
  float* out = (float*)d_out;

  char* ws = (char*)d_ws;
  unsigned short* h_t   = (unsigned short*)(ws);                      // 8 MB, reused as hout_t
  unsigned short* q_t   = (unsigned short*)(ws + ((size_t)8  << 20));
  unsigned short* k_t   = (unsigned short*)(ws + ((size_t)16 << 20));
  unsigned short* v_    = (unsigned short*)(ws + ((size_t)24 << 20));
  unsigned short* wqkv  = (unsigned short*)(ws + ((size_t)32 << 20));
  unsigned short* wproj = (unsigned short*)(ws + ((size_t)34 << 20));
  float* stats          = (float*)(ws + ((size_t)35 << 20));
  unsigned short* o_part = (unsigned short*)(ws + ((size_t)36 << 20)); // 16 MB
  float* l_part          = (float*)(ws + ((size_t)52 << 20));          // 512 KB
  unsigned short* hout_t = h_t;

  const bool split = ws_size >= (((size_t)52 << 20) + ((size_t)1 << 19));

  setup_kernel<<<dim3(1088), dim3(256), 0, stream>>>(x, stats, qkv_w, wqkv, proj_w, wproj);
  gn_apply_t<<<dim3(64, 8, 2), dim3(256), 0, stream>>>(x, stats, gn_w, gn_b, h_t);
  qkv_gemm<<<dim3(32, 12, 2), dim3(256), 0, stream>>>(wqkv, h_t, q_t, k_t, v_);
  if (split) {
    attn_kernel<1><<<dim3(16, 32, 2), dim3(256), 0, stream>>>(q_t, k_t, v_, nullptr,
                                                              o_part, l_part);
    attn_combine<<<dim3(16, 64), dim3(256), 0, stream>>>(o_part, l_part, hout_t);
  } else {
    attn_kernel<0><<<dim3(16, 32), dim3(256), 0, stream>>>(q_t, k_t, v_, hout_t,
                                                           nullptr, nullptr);
  }
  proj_gemm<<<dim3(32, 8, 2), dim3(256), 0, stream>>>(wproj, hout_t, out, x, proj_b);
}

// Round 7
// 234.693 us; speedup vs baseline: 1.1983x; 1.1983x over previous
//
#include <hip/hip_runtime.h>
#include <math.h>

typedef __attribute__((ext_vector_type(8))) short short8;
typedef __attribute__((ext_vector_type(4))) short short4v;
typedef __attribute__((ext_vector_type(4))) float floatx4;
typedef __attribute__((ext_vector_type(16))) float floatx16;

__device__ __forceinline__ unsigned short f2bf(float f) {
  union { float f; unsigned int u; } v; v.f = f;
  unsigned int r = v.u + 0x7fffu + ((v.u >> 16) & 1u);
  return (unsigned short)(r >> 16);
}

__device__ __forceinline__ float bf2f(unsigned short h) {
  union { unsigned int u; float f; } v; v.u = ((unsigned int)h) << 16;
  return v.f;
}

__device__ __forceinline__ unsigned int pack2(unsigned short a, unsigned short b) {
  return (unsigned int)a | ((unsigned int)b << 16);
}

__device__ __forceinline__ unsigned int rbits(float f) {
  union { float f; unsigned int u; } v; v.f = f;
  return v.u + 0x8000u;  // round-half-up to bf16 when >>16
}

__device__ __forceinline__ float fast_exp2(float x) {
#if __has_builtin(__builtin_amdgcn_exp2f)
  return __builtin_amdgcn_exp2f(x);
#else
  return exp2f(x);
#endif
}

// async global->LDS, 16B per lane. LDS dest is wave-uniform base + lane*16.
__device__ __forceinline__ void async16(const unsigned short* gp, unsigned short* lp) {
  __builtin_amdgcn_global_load_lds(
      (__attribute__((address_space(1))) void*)(gp),
      (__attribute__((address_space(3))) void*)(lp), 16, 0, 0);
}

// ------------------------------------------------- setup: GN stats + w casts
__global__ void setup_kernel(const float* __restrict__ x, float* __restrict__ stats,
                             const float* __restrict__ qkv_w, unsigned short* __restrict__ wqkv,
                             const float* __restrict__ proj_w, unsigned short* __restrict__ wproj) {
  if (blockIdx.x < 64) {
    int bg = blockIdx.x;
    const float4* p = (const float4*)(x + (size_t)bg * 65536);
    float s = 0.f, ss = 0.f;
    for (int i = threadIdx.x; i < 16384; i += 256) {
      float4 v = p[i];
      s  += v.x + v.y + v.z + v.w;
      ss += v.x*v.x + v.y*v.y + v.z*v.z + v.w*v.w;
    }
    #pragma unroll
    for (int off = 32; off >= 1; off >>= 1) {
      s  += __shfl_xor(s,  off, 64);
      ss += __shfl_xor(ss, off, 64);
    }
    __shared__ float red[2][4];
    int wv = threadIdx.x >> 6;
    if ((threadIdx.x & 63) == 0) { red[0][wv] = s; red[1][wv] = ss; }
    __syncthreads();
    if (threadIdx.x == 0) {
      s  = red[0][0] + red[0][1] + red[0][2] + red[0][3];
      ss = red[1][0] + red[1][1] + red[1][2] + red[1][3];
      float mean = s * (1.f/65536.f);
      float var  = ss * (1.f/65536.f) - mean*mean;
      stats[2*bg]   = mean;
      stats[2*bg+1] = rsqrtf(var + 1e-5f);
    }
  } else {
    int i = (blockIdx.x - 64) * 256 + threadIdx.x;
    const float* s; unsigned short* d;
    if (i < 196608) { s = qkv_w; d = wqkv; }
    else { i -= 196608; s = proj_w; d = wproj; }
    float4 vv = ((const float4*)s)[i];
    uint2 o;
    o.x = pack2(f2bf(vv.x), f2bf(vv.y));
    o.y = pack2(f2bf(vv.z), f2bf(vv.w));
    ((uint2*)d)[i] = o;
  }
}

// normalize + cast bf16 + transpose to token-major h_t[B][HW][C]
__global__ void gn_apply_t(const float* __restrict__ x, const float* __restrict__ stats,
                           const float* __restrict__ gw, const float* __restrict__ gb,
                           unsigned short* __restrict__ h_t) {
  __shared__ __align__(16) unsigned short tile[64][72];
  const int b = blockIdx.z, c0 = blockIdx.y * 64, hw0 = blockIdx.x * 64;
  const int t = threadIdx.x;
  {
    const int cl = t >> 2;
    const int hs = (t & 3) * 16;
    const int c  = c0 + cl;
    const int g  = c >> 4;
    const float mean = stats[2*(b*32 + g)];
    const float rstd = stats[2*(b*32 + g) + 1];
    const float w  = gw[c] * rstd;
    const float bb = gb[c] - mean * w;
    const float4* src = (const float4*)(x + ((size_t)(b*512 + c))*4096 + hw0 + hs);
    #pragma unroll
    for (int i = 0; i < 4; i++) {
      float4 vv = src[i];
      unsigned short* d = &tile[cl][hs + i*4];
      d[0] = f2bf(vv.x*w + bb); d[1] = f2bf(vv.y*w + bb);
      d[2] = f2bf(vv.z*w + bb); d[3] = f2bf(vv.w*w + bb);
    }
  }
  __syncthreads();
  {
    const int hwl = t >> 2;
    const int cs  = (t & 3) * 16;
    uint4 w0, w1;
    w0.x = pack2(tile[cs+ 0][hwl], tile[cs+ 1][hwl]);
    w0.y = pack2(tile[cs+ 2][hwl], tile[cs+ 3][hwl]);
    w0.z = pack2(tile[cs+ 4][hwl], tile[cs+ 5][hwl]);
    w0.w = pack2(tile[cs+ 6][hwl], tile[cs+ 7][hwl]);
    w1.x = pack2(tile[cs+ 8][hwl], tile[cs+ 9][hwl]);
    w1.y = pack2(tile[cs+10][hwl], tile[cs+11][hwl]);
    w1.z = pack2(tile[cs+12][hwl], tile[cs+13][hwl]);
    w1.w = pack2(tile[cs+14][hwl], tile[cs+15][hwl]);
    unsigned short* dst = h_t + ((size_t)(b*4096 + hw0 + hwl))*512 + c0 + cs;
    *(uint4*)dst       = w0;
    *(uint4*)(dst + 8) = w1;
  }
}

// ---------------------------------------------------------------- QKV GEMM
__global__ __launch_bounds__(256, 2)
void qkv_gemm(const unsigned short* __restrict__ A,
              const unsigned short* __restrict__ Bt,
              unsigned short* __restrict__ q_t,
              unsigned short* __restrict__ k_t,
              unsigned short* __restrict__ v_) {
  __shared__ __align__(16) unsigned short As[128*32];
  __shared__ __align__(16) unsigned short Bs[128*32];
  const int b   = blockIdx.z;
  const int n0  = blockIdx.x * 128;
  const int o0  = blockIdx.y * 128;
  const int tid = threadIdx.x;
  const int wave = tid >> 6, lane = tid & 63;
  const int wr = wave >> 1, wc = wave & 1;
  const int fm = lane & 15, fq = lane >> 4;
  const int srow = lane >> 2, scol = (lane & 3) * 8;

  const unsigned short* Ab = A + (size_t)o0 * 512;
  const unsigned short* Bb = Bt + ((size_t)b*4096 + n0) * 512;

  bool vsw[4];
  #pragma unroll
  for (int fr = 0; fr < 4; fr++) {
    const int ob = o0 + wr*64 + fr*16;
    vsw[fr] = ((ob % 192) >> 6) == 2;
  }

  floatx4 acc[4][4];
  #pragma unroll
  for (int i = 0; i < 4; i++)
    #pragma unroll
    for (int j = 0; j < 4; j++) acc[i][j] = (floatx4){0.f,0.f,0.f,0.f};

  for (int k0 = 0; k0 < 512; k0 += 32) {
    __syncthreads();
    #pragma unroll
    for (int cc = 0; cc < 2; cc++) {
      int ch = wave*2 + cc;
      async16(Ab + (size_t)(ch*16 + srow)*512 + k0 + scol, &As[ch*512]);
      async16(Bb + (size_t)(ch*16 + srow)*512 + k0 + scol, &Bs[ch*512]);
    }
    __syncthreads();
    short8 af[4], bf[4];
    #pragma unroll
    for (int f = 0; f < 4; f++) {
      af[f] = *(const short8*)&As[(wr*64 + f*16 + fm)*32 + fq*8];
      bf[f] = *(const short8*)&Bs[(wc*64 + f*16 + fm)*32 + fq*8];
    }
    #pragma unroll
    for (int fr = 0; fr < 4; fr++) {
      if (vsw[fr]) {
        #pragma unroll
        for (int fc = 0; fc < 4; fc++)
          acc[fr][fc] = __builtin_amdgcn_mfma_f32_16x16x32_bf16(bf[fc], af[fr], acc[fr][fc], 0, 0, 0);
      } else {
        #pragma unroll
        for (int fc = 0; fc < 4; fc++)
          acc[fr][fc] = __builtin_amdgcn_mfma_f32_16x16x32_bf16(af[fr], bf[fc], acc[fr][fc], 0, 0, 0);
      }
    }
  }

  #pragma unroll
  for (int fr = 0; fr < 4; fr++) {
    const int ob     = o0 + wr*64 + fr*16;
    const int head   = ob / 192;
    const int rem    = ob % 192;
    const int region = rem >> 6;             // 0=q 1=k 2=v
    const int bhh    = b*8 + head;
    #pragma unroll
    for (int fc = 0; fc < 4; fc++) {
      if (region == 0) {
        const int i = n0 + wc*64 + fc*16 + fm;
        const int dsub = (rem & 63) + fq*4;
        unsigned short t4[4];
        #pragma unroll
        for (int r = 0; r < 4; r++) t4[r] = f2bf(acc[fr][fc][r] * 0.18033688f);
        uint2 o; o.x = pack2(t4[0], t4[1]); o.y = pack2(t4[2], t4[3]);
        *(uint2*)&q_t[((size_t)bhh*4096 + i)*64 + dsub] = o;
      } else if (region == 1) {
        const int i = n0 + wc*64 + fc*16 + fm;
        const int dsub = (rem & 63) + fq*4;
        unsigned short t4[4];
        #pragma unroll
        for (int r = 0; r < 4; r++) t4[r] = f2bf(acc[fr][fc][r]);
        uint2 o; o.x = pack2(t4[0], t4[1]); o.y = pack2(t4[2], t4[3]);
        *(uint2*)&k_t[((size_t)bhh*4096 + i)*64 + dsub] = o;
      } else {
        const int dsub = (rem & 63) + fm;
        const int tok0 = n0 + wc*64 + fc*16 + fq*4;
        unsigned short t4[4];
        #pragma unroll
        for (int r = 0; r < 4; r++) t4[r] = f2bf(acc[fr][fc][r]);
        uint2 o; o.x = pack2(t4[0], t4[1]); o.y = pack2(t4[2], t4[3]);
        *(uint2*)&v_[((size_t)bhh*64 + dsub)*4096 + tok0] = o;
      }
    }
  }
}

// ---------------------------------------------------------------- proj GEMM
// 64x128 tile, grid (32,8,2)=512 blocks (2/CU). out = x + bias + acc (fp32).
__global__ __launch_bounds__(256, 2)
void proj_gemm(const unsigned short* __restrict__ A,     // wproj [512][512]
               const unsigned short* __restrict__ Bt,    // hout_t [B][4096][512]
               float* __restrict__ outp,
               const float* __restrict__ xres,
               const float* __restrict__ pbias) {
  __shared__ __align__(16) unsigned short As[64*32];
  __shared__ __align__(16) unsigned short Bs[128*32];
  const int b   = blockIdx.z;
  const int n0  = blockIdx.x * 128;
  const int o0  = blockIdx.y * 64;
  const int tid = threadIdx.x;
  const int wave = tid >> 6, lane = tid & 63;
  const int wr = wave >> 1, wc = wave & 1;
  const int fm = lane & 15, fq = lane >> 4;
  const int srow = lane >> 2, scol = (lane & 3) * 8;

  const unsigned short* Ab = A + (size_t)o0 * 512;
  const unsigned short* Bb = Bt + ((size_t)b*4096 + n0) * 512;

  floatx4 acc[2][4];
  #pragma unroll
  for (int i = 0; i < 2; i++)
    #pragma unroll
    for (int j = 0; j < 4; j++) acc[i][j] = (floatx4){0.f,0.f,0.f,0.f};

  for (int k0 = 0; k0 < 512; k0 += 32) {
    __syncthreads();
    async16(Ab + (size_t)(wave*16 + srow)*512 + k0 + scol, &As[wave*512]);
    #pragma unroll
    for (int cc = 0; cc < 2; cc++) {
      int ch = wave*2 + cc;
      async16(Bb + (size_t)(ch*16 + srow)*512 + k0 + scol, &Bs[ch*512]);
    }
    __syncthreads();
    short8 af[2], bf[4];
    #pragma unroll
    for (int f = 0; f < 2; f++)
      af[f] = *(const short8*)&As[(wr*32 + f*16 + fm)*32 + fq*8];
    #pragma unroll
    for (int f = 0; f < 4; f++)
      bf[f] = *(const short8*)&Bs[(wc*64 + f*16 + fm)*32 + fq*8];
    #pragma unroll
    for (int fr = 0; fr < 2; fr++)
      #pragma unroll
      for (int fc = 0; fc < 4; fc++)
        acc[fr][fc] = __builtin_amdgcn_mfma_f32_16x16x32_bf16(af[fr], bf[fc], acc[fr][fc], 0, 0, 0);
  }

  #pragma unroll
  for (int fr = 0; fr < 2; fr++)
    #pragma unroll
    for (int fc = 0; fc < 4; fc++) {
      const int i = n0 + wc*64 + fc*16 + fm;
      #pragma unroll
      for (int r = 0; r < 4; r++) {
        const int o = o0 + wr*32 + fr*16 + fq*4 + r;
        const size_t idx = ((size_t)b*512 + o)*4096 + i;
        outp[idx] = xres[idx] + pbias[o] + acc[fr][fc][r];
      }
    }
}

// ---------------------------------------------------------------- attention
// R5 structure (measured 89 µs): K+V double-buffered in LDS via register
// prefetch (coalesced global loads, tile shared by all 4 waves), P stays in
// registers (S^T C-layout == PV A-layout per 8-j subtile), V j-interleaved
// for b128 PV B-frags, ONE barrier per iter, split-j x2 with bf16 O-partials.
template <int SPLIT>
__global__ __launch_bounds__(256, 4)
void attn_kernel(const unsigned short* __restrict__ q_t,
                 const unsigned short* __restrict__ k_t,
                 const unsigned short* __restrict__ v_,
                 unsigned short* __restrict__ hout_t,
                 unsigned short* __restrict__ o_part,
                 float* __restrict__ l_part) {
  __shared__ __align__(16) unsigned short Ks[2][64*72];   // [j][k], +pad
  __shared__ __align__(16) unsigned short Vs[2][64*72];   // [d][j-interleaved], +pad

  const int bh  = blockIdx.x;
  const int q0  = blockIdx.y * 128;
  const int js  = SPLIT ? blockIdx.z : 0;
  const int nit = SPLIT ? 32 : 64;
  const int jbase = js * 2048;
  const int tid = threadIdx.x;
  const int wave = tid >> 6, lane = tid & 63;
  const int ln = lane & 31, h = lane >> 5;

  // Q B-frags (32x32x16): B[k=kc*16+h*8+t][n=ln], i = q0+wave*32+ln
  short8 qf[4];
  {
    const unsigned short* qrow = q_t + ((size_t)bh*4096 + q0 + wave*32 + ln)*64;
    #pragma unroll
    for (int kc = 0; kc < 4; kc++)
      qf[kc] = *(const short8*)(qrow + kc*16 + h*8);
  }

  const floatx16 z16 = {0.f,0.f,0.f,0.f,0.f,0.f,0.f,0.f,
                        0.f,0.f,0.f,0.f,0.f,0.f,0.f,0.f};
  floatx16 o_acc[2];
  o_acc[0] = z16; o_acc[1] = z16;
  float l = 0.f;

  const int sr = tid >> 3;          // 0..31
  const int sc = (tid & 7) * 8;     // source 8-short chunk
  const int cch = tid & 7;          // chunk id within 64-j row
  const int vpos = ((cch >> 2) * 32) + ((cch & 3) * 4);
  const unsigned short* kbase = k_t + (size_t)bh*262144;
  const unsigned short* vbase = v_  + (size_t)bh*262144;

  // preload tile 0 into registers
  uint4 kr0 = *(const uint4*)&kbase[(size_t)(jbase + sr)*64 + sc];
  uint4 kr1 = *(const uint4*)&kbase[(size_t)(jbase + sr + 32)*64 + sc];
  uint4 vr0 = *(const uint4*)&vbase[(size_t)sr*4096 + jbase + sc];
  uint4 vr1 = *(const uint4*)&vbase[(size_t)(sr+32)*4096 + jbase + sc];

  for (int it = 0; it < nit; it++) {
    unsigned short* Kc = Ks[it & 1];
    unsigned short* Vc = Vs[it & 1];
    *(uint4*)&Kc[sr*72 + sc]      = kr0;
    *(uint4*)&Kc[(sr+32)*72 + sc] = kr1;
    *(uint2*)&Vc[sr*72 + vpos]           = *(const uint2*)&vr0;
    *(uint2*)&Vc[sr*72 + vpos + 16]      = *((const uint2*)&vr0 + 1);
    *(uint2*)&Vc[(sr+32)*72 + vpos]      = *(const uint2*)&vr1;
    *(uint2*)&Vc[(sr+32)*72 + vpos + 16] = *((const uint2*)&vr1 + 1);
    __syncthreads();

    // issue next tile's global loads (latency hidden behind compute)
    {
      const int jn = jbase + (((it + 1) & (nit - 1)) * 64);
      kr0 = *(const uint4*)&kbase[(size_t)(jn + sr)*64 + sc];
      kr1 = *(const uint4*)&kbase[(size_t)(jn + sr + 32)*64 + sc];
      vr0 = *(const uint4*)&vbase[(size_t)sr*4096 + jn + sc];
      vr1 = *(const uint4*)&vbase[(size_t)(sr+32)*4096 + jn + sc];
    }

    // one 32-j subtile (mj) at a time: QK -> exp/pack -> PV
    #pragma unroll
    for (int mj = 0; mj < 2; mj++) {
      // S^T = K Q^T
      floatx16 st;
      {
        short8 kA = *(const short8*)&Kc[(mj*32 + ln)*72 + h*8];
        st = __builtin_amdgcn_mfma_f32_32x32x16_bf16(kA, qf[0], z16, 0, 0, 0);
      }
      #pragma unroll
      for (int kc = 1; kc < 4; kc++) {
        short8 kA = *(const short8*)&Kc[(mj*32 + ln)*72 + kc*16 + h*8];
        st = __builtin_amdgcn_mfma_f32_32x32x16_bf16(kA, qf[kc], st, 0, 0, 0);
      }

      // p = exp2(s'), accumulate l, pack to bf16 pairs
      unsigned pk[8];
      #pragma unroll
      for (int rp = 0; rp < 8; rp++) {
        float p0 = fast_exp2(st[2*rp]);
        float p1 = fast_exp2(st[2*rp + 1]);
        l += p0 + p1;
        pk[rp] = __builtin_amdgcn_perm(rbits(p1), rbits(p0), 0x07060302u);
      }

      // O += P V via 32x32x8 (V b128 covers 2 subtiles, interleaved layout)
      #pragma unroll
      for (int t2 = 0; t2 < 2; t2++) {
        union { unsigned u[2]; short4v s; } a0, a1;
        a0.u[0] = pk[4*t2];     a0.u[1] = pk[4*t2 + 1];
        a1.u[0] = pk[4*t2 + 2]; a1.u[1] = pk[4*t2 + 3];
        #pragma unroll
        for (int dn = 0; dn < 2; dn++) {
          short8 vv = *(const short8*)&Vc[(dn*32 + ln)*72 + mj*32 + h*16 + t2*8];
          short4v vlo = __builtin_shufflevector(vv, vv, 0, 1, 2, 3);
          short4v vhi = __builtin_shufflevector(vv, vv, 4, 5, 6, 7);
          o_acc[dn] = __builtin_amdgcn_mfma_f32_32x32x8bf16_1k(a0.s, vlo, o_acc[dn], 0, 0, 0);
          o_acc[dn] = __builtin_amdgcn_mfma_f32_32x32x8bf16_1k(a1.s, vhi, o_acc[dn], 0, 0, 0);
        }
      }
    }
  }

  // column sums complete within lane pairs (h=0/1)
  l += __shfl_xor(l, 32, 64);

  if (SPLIT) {
    unsigned short* op = o_part + (((size_t)(js*16 + bh)*4096 + q0 + wave*32) * 64);
    #pragma unroll
    for (int r = 0; r < 16; r++) {
      const int il = (r & 3) + 8*(r >> 2) + 4*h;
      op[(size_t)il*64 + ln]      = f2bf(o_acc[0][r]);
      op[(size_t)il*64 + 32 + ln] = f2bf(o_acc[1][r]);
    }
    if (lane < 32)
      l_part[(size_t)(js*16 + bh)*4096 + q0 + wave*32 + lane] = l;
  } else {
    const float linv = 1.f / l;
    const int bb = bh >> 3;
    const int cb = (bh & 7) * 64;
    #pragma unroll
    for (int r = 0; r < 16; r++) {
      const int il = (r & 3) + 8*(r >> 2) + 4*h;
      const float inv = __shfl(linv, il, 64);
      const int i = q0 + wave*32 + il;
      unsigned short* dst = &hout_t[((size_t)bb*4096 + i)*512 + cb + ln];
      dst[0]  = f2bf(o_acc[0][r] * inv);
      dst[32] = f2bf(o_acc[1][r] * inv);
    }
  }
}

// combine: hout = (O0+O1)/(l0+l1), bf16 token-major
__global__ void attn_combine(const unsigned short* __restrict__ o_part,
                             const float* __restrict__ l_part,
                             unsigned short* __restrict__ hout_t) {
  const int bh = blockIdx.x;
  const int i0 = blockIdx.y * 64;
  const int t  = threadIdx.x;
  const int d4 = (t & 15) * 4;
  const int il = t >> 4;
  const int bb = bh >> 3;
  const int cb = (bh & 7) * 64;
  const size_t JS = (size_t)16 * 4096 * 64;   // js stride in o_part
  #pragma unroll
  for (int p = 0; p < 4; p++) {
    const int i = i0 + p*16 + il;
    const size_t ob = ((size_t)bh*4096 + i)*64 + d4;
    uint2 a = *(const uint2*)&o_part[ob];
    uint2 b = *(const uint2*)&o_part[ob + JS];
    const size_t lb = (size_t)bh*4096 + i;
    const float inv = 1.f / (l_part[lb] + l_part[lb + 65536]);
    float o0 = (bf2f((unsigned short)(a.x & 0xffff)) + bf2f((unsigned short)(b.x & 0xffff))) * inv;
    float o1 = (bf2f((unsigned short)(a.x >> 16))    + bf2f((unsigned short)(b.x >> 16)))    * inv;
    float o2 = (bf2f((unsigned short)(a.y & 0xffff)) + bf2f((unsigned short)(b.y & 0xffff))) * inv;
    float o3 = (bf2f((unsigned short)(a.y >> 16))    + bf2f((unsigned short)(b.y >> 16)))    * inv;
    uint2 w;
    w.x = pack2(f2bf(o0), f2bf(o1));
    w.y = pack2(f2bf(o2), f2bf(o3));
    *(uint2*)&hout_t[((size_t)bb*4096 + i)*512 + cb + d4] = w;
  }
}

// ---------------------------------------------------------------- launcher
extern "C" void kernel_launch(void* const* d_in, const int* in_sizes, int n_in,
                              void* d_out, int out_size, void* d_ws, size_t ws_size,
                              hipStream_t stream) {
  (void)in_sizes; (void)n_in; (void)out_size;
  const float* x      = (const float*)d_in[0];
  const float* qkv_w  = (const float*)d_in[1];
  const float* proj_w = (const float*)d_in[2];
  const float* proj_b = (const float*)d_in[3];
  const float* gn_w   = (const float*)d_in[4];
  const float* gn_b   = (const float*)d_in[5];
  float* out = (float*)d_out;

  char* ws = (char*)d_ws;
  unsigned short* h_t   = (unsigned short*)(ws);                      // 8 MB, reused as hout_t
  unsigned short* q_t   = (unsigned short*)(ws + ((size_t)8  << 20));
  unsigned short* k_t   = (unsigned short*)(ws + ((size_t)16 << 20));
  unsigned short* v_    = (unsigned short*)(ws + ((size_t)24 << 20));
  unsigned short* wqkv  = (unsigned short*)(ws + ((size_t)32 << 20));
  unsigned short* wproj = (unsigned short*)(ws + ((size_t)34 << 20));
  float* stats          = (float*)(ws + ((size_t)35 << 20));
  unsigned short* o_part = (unsigned short*)(ws + ((size_t)36 << 20)); // 16 MB
  float* l_part          = (float*)(ws + ((size_t)52 << 20));          // 512 KB
  unsigned short* hout_t = h_t;

  const bool split = ws_size >= (((size_t)52 << 20) + ((size_t)1 << 19));

  setup_kernel<<<dim3(1088), dim3(256), 0, stream>>>(x, stats, qkv_w, wqkv, proj_w, wproj);
  gn_apply_t<<<dim3(64, 8, 2), dim3(256), 0, stream>>>(x, stats, gn_w, gn_b, h_t);
  qkv_gemm<<<dim3(32, 12, 2), dim3(256), 0, stream>>>(wqkv, h_t, q_t, k_t, v_);
  if (split) {
    attn_kernel<1><<<dim3(16, 32, 2), dim3(256), 0, stream>>>(q_t, k_t, v_, nullptr,
                                                              o_part, l_part);
    attn_combine<<<dim3(16, 64), dim3(256), 0, stream>>>(o_part, l_part, hout_t);
  } else {
    attn_kernel<0><<<dim3(16, 32), dim3(256), 0, stream>>>(q_t, k_t, v_, hout_t,
                                                           nullptr, nullptr);
  }
  proj_gemm<<<dim3(32, 8, 2), dim3(256), 0, stream>>>(wproj, hout_t, out, x, proj_b);
}

// Round 8
// 227.143 us; speedup vs baseline: 1.2381x; 1.0332x over previous
//
#include <hip/hip_runtime.h>
#include <math.h>

typedef __attribute__((ext_vector_type(8))) short short8;
typedef __attribute__((ext_vector_type(4))) short short4v;
typedef __attribute__((ext_vector_type(4))) float floatx4;
typedef __attribute__((ext_vector_type(16))) float floatx16;

__device__ __forceinline__ unsigned short f2bf(float f) {
  union { float f; unsigned int u; } v; v.f = f;
  unsigned int r = v.u + 0x7fffu + ((v.u >> 16) & 1u);
  return (unsigned short)(r >> 16);
}

__device__ __forceinline__ float bf2f(unsigned short h) {
  union { unsigned int u; float f; } v; v.u = ((unsigned int)h) << 16;
  return v.f;
}

__device__ __forceinline__ unsigned int pack2(unsigned short a, unsigned short b) {
  return (unsigned int)a | ((unsigned int)b << 16);
}

__device__ __forceinline__ unsigned int rbits(float f) {
  union { float f; unsigned int u; } v; v.f = f;
  return v.u + 0x8000u;  // round-half-up to bf16 when >>16
}

__device__ __forceinline__ float fast_exp2(float x) {
#if __has_builtin(__builtin_amdgcn_exp2f)
  return __builtin_amdgcn_exp2f(x);
#else
  return exp2f(x);
#endif
}

// async global->LDS, 16B per lane. LDS dest is wave-uniform base + lane*16.
__device__ __forceinline__ void async16(const unsigned short* gp, unsigned short* lp) {
  __builtin_amdgcn_global_load_lds(
      (__attribute__((address_space(1))) void*)(gp),
      (__attribute__((address_space(3))) void*)(lp), 16, 0, 0);
}

// ------------------------------------------------- setup: GN stats + w casts
__global__ void setup_kernel(const float* __restrict__ x, float* __restrict__ stats,
                             const float* __restrict__ qkv_w, unsigned short* __restrict__ wqkv,
                             const float* __restrict__ proj_w, unsigned short* __restrict__ wproj) {
  if (blockIdx.x < 64) {
    int bg = blockIdx.x;
    const float4* p = (const float4*)(x + (size_t)bg * 65536);
    float s = 0.f, ss = 0.f;
    for (int i = threadIdx.x; i < 16384; i += 256) {
      float4 v = p[i];
      s  += v.x + v.y + v.z + v.w;
      ss += v.x*v.x + v.y*v.y + v.z*v.z + v.w*v.w;
    }
    #pragma unroll
    for (int off = 32; off >= 1; off >>= 1) {
      s  += __shfl_xor(s,  off, 64);
      ss += __shfl_xor(ss, off, 64);
    }
    __shared__ float red[2][4];
    int wv = threadIdx.x >> 6;
    if ((threadIdx.x & 63) == 0) { red[0][wv] = s; red[1][wv] = ss; }
    __syncthreads();
    if (threadIdx.x == 0) {
      s  = red[0][0] + red[0][1] + red[0][2] + red[0][3];
      ss = red[1][0] + red[1][1] + red[1][2] + red[1][3];
      float mean = s * (1.f/65536.f);
      float var  = ss * (1.f/65536.f) - mean*mean;
      stats[2*bg]   = mean;
      stats[2*bg+1] = rsqrtf(var + 1e-5f);
    }
  } else {
    int i = (blockIdx.x - 64) * 256 + threadIdx.x;
    const float* s; unsigned short* d;
    if (i < 196608) { s = qkv_w; d = wqkv; }
    else { i -= 196608; s = proj_w; d = wproj; }
    float4 vv = ((const float4*)s)[i];
    uint2 o;
    o.x = pack2(f2bf(vv.x), f2bf(vv.y));
    o.y = pack2(f2bf(vv.z), f2bf(vv.w));
    ((uint2*)d)[i] = o;
  }
}

// normalize + cast bf16 + transpose to token-major h_t[B][HW][C]
__global__ void gn_apply_t(const float* __restrict__ x, const float* __restrict__ stats,
                           const float* __restrict__ gw, const float* __restrict__ gb,
                           unsigned short* __restrict__ h_t) {
  __shared__ __align__(16) unsigned short tile[64][72];
  const int b = blockIdx.z, c0 = blockIdx.y * 64, hw0 = blockIdx.x * 64;
  const int t = threadIdx.x;
  {
    const int cl = t >> 2;
    const int hs = (t & 3) * 16;
    const int c  = c0 + cl;
    const int g  = c >> 4;
    const float mean = stats[2*(b*32 + g)];
    const float rstd = stats[2*(b*32 + g) + 1];
    const float w  = gw[c] * rstd;
    const float bb = gb[c] - mean * w;
    const float4* src = (const float4*)(x + ((size_t)(b*512 + c))*4096 + hw0 + hs);
    #pragma unroll
    for (int i = 0; i < 4; i++) {
      float4 vv = src[i];
      unsigned short* d = &tile[cl][hs + i*4];
      d[0] = f2bf(vv.x*w + bb); d[1] = f2bf(vv.y*w + bb);
      d[2] = f2bf(vv.z*w + bb); d[3] = f2bf(vv.w*w + bb);
    }
  }
  __syncthreads();
  {
    const int hwl = t >> 2;
    const int cs  = (t & 3) * 16;
    uint4 w0, w1;
    w0.x = pack2(tile[cs+ 0][hwl], tile[cs+ 1][hwl]);
    w0.y = pack2(tile[cs+ 2][hwl], tile[cs+ 3][hwl]);
    w0.z = pack2(tile[cs+ 4][hwl], tile[cs+ 5][hwl]);
    w0.w = pack2(tile[cs+ 6][hwl], tile[cs+ 7][hwl]);
    w1.x = pack2(tile[cs+ 8][hwl], tile[cs+ 9][hwl]);
    w1.y = pack2(tile[cs+10][hwl], tile[cs+11][hwl]);
    w1.z = pack2(tile[cs+12][hwl], tile[cs+13][hwl]);
    w1.w = pack2(tile[cs+14][hwl], tile[cs+15][hwl]);
    unsigned short* dst = h_t + ((size_t)(b*4096 + hw0 + hwl))*512 + c0 + cs;
    *(uint4*)dst       = w0;
    *(uint4*)(dst + 8) = w1;
  }
}

// ---------------------------------------------------------------- QKV GEMM
// launch_bounds(256,3): 768 blocks co-resident (3/CU) -> no 1.5-round tail.
__global__ __launch_bounds__(256, 3)
void qkv_gemm(const unsigned short* __restrict__ A,
              const unsigned short* __restrict__ Bt,
              unsigned short* __restrict__ q_t,
              unsigned short* __restrict__ k_t,
              unsigned short* __restrict__ v_) {
  __shared__ __align__(16) unsigned short As[128*32];
  __shared__ __align__(16) unsigned short Bs[128*32];
  const int b   = blockIdx.z;
  const int n0  = blockIdx.x * 128;
  const int o0  = blockIdx.y * 128;
  const int tid = threadIdx.x;
  const int wave = tid >> 6, lane = tid & 63;
  const int wr = wave >> 1, wc = wave & 1;
  const int fm = lane & 15, fq = lane >> 4;
  const int srow = lane >> 2, scol = (lane & 3) * 8;

  const unsigned short* Ab = A + (size_t)o0 * 512;
  const unsigned short* Bb = Bt + ((size_t)b*4096 + n0) * 512;

  bool vsw[4];
  #pragma unroll
  for (int fr = 0; fr < 4; fr++) {
    const int ob = o0 + wr*64 + fr*16;
    vsw[fr] = ((ob % 192) >> 6) == 2;
  }

  floatx4 acc[4][4];
  #pragma unroll
  for (int i = 0; i < 4; i++)
    #pragma unroll
    for (int j = 0; j < 4; j++) acc[i][j] = (floatx4){0.f,0.f,0.f,0.f};

  for (int k0 = 0; k0 < 512; k0 += 32) {
    __syncthreads();
    #pragma unroll
    for (int cc = 0; cc < 2; cc++) {
      int ch = wave*2 + cc;
      async16(Ab + (size_t)(ch*16 + srow)*512 + k0 + scol, &As[ch*512]);
      async16(Bb + (size_t)(ch*16 + srow)*512 + k0 + scol, &Bs[ch*512]);
    }
    __syncthreads();
    short8 af[4], bf[4];
    #pragma unroll
    for (int f = 0; f < 4; f++) {
      af[f] = *(const short8*)&As[(wr*64 + f*16 + fm)*32 + fq*8];
      bf[f] = *(const short8*)&Bs[(wc*64 + f*16 + fm)*32 + fq*8];
    }
    #pragma unroll
    for (int fr = 0; fr < 4; fr++) {
      if (vsw[fr]) {
        #pragma unroll
        for (int fc = 0; fc < 4; fc++)
          acc[fr][fc] = __builtin_amdgcn_mfma_f32_16x16x32_bf16(bf[fc], af[fr], acc[fr][fc], 0, 0, 0);
      } else {
        #pragma unroll
        for (int fc = 0; fc < 4; fc++)
          acc[fr][fc] = __builtin_amdgcn_mfma_f32_16x16x32_bf16(af[fr], bf[fc], acc[fr][fc], 0, 0, 0);
      }
    }
  }

  #pragma unroll
  for (int fr = 0; fr < 4; fr++) {
    const int ob     = o0 + wr*64 + fr*16;
    const int head   = ob / 192;
    const int rem    = ob % 192;
    const int region = rem >> 6;             // 0=q 1=k 2=v
    const int bhh    = b*8 + head;
    #pragma unroll
    for (int fc = 0; fc < 4; fc++) {
      if (region == 0) {
        const int i = n0 + wc*64 + fc*16 + fm;
        const int dsub = (rem & 63) + fq*4;
        unsigned short t4[4];
        #pragma unroll
        for (int r = 0; r < 4; r++) t4[r] = f2bf(acc[fr][fc][r] * 0.18033688f);
        uint2 o; o.x = pack2(t4[0], t4[1]); o.y = pack2(t4[2], t4[3]);
        *(uint2*)&q_t[((size_t)bhh*4096 + i)*64 + dsub] = o;
      } else if (region == 1) {
        const int i = n0 + wc*64 + fc*16 + fm;
        const int dsub = (rem & 63) + fq*4;
        unsigned short t4[4];
        #pragma unroll
        for (int r = 0; r < 4; r++) t4[r] = f2bf(acc[fr][fc][r]);
        uint2 o; o.x = pack2(t4[0], t4[1]); o.y = pack2(t4[2], t4[3]);
        *(uint2*)&k_t[((size_t)bhh*4096 + i)*64 + dsub] = o;
      } else {
        const int dsub = (rem & 63) + fm;
        const int tok0 = n0 + wc*64 + fc*16 + fq*4;
        unsigned short t4[4];
        #pragma unroll
        for (int r = 0; r < 4; r++) t4[r] = f2bf(acc[fr][fc][r]);
        uint2 o; o.x = pack2(t4[0], t4[1]); o.y = pack2(t4[2], t4[3]);
        *(uint2*)&v_[((size_t)bhh*64 + dsub)*4096 + tok0] = o;
      }
    }
  }
}

// ---------------------------------------------------------------- proj GEMM
__global__ __launch_bounds__(256, 2)
void proj_gemm(const unsigned short* __restrict__ A,     // wproj [512][512]
               const unsigned short* __restrict__ Bt,    // hout_t [B][4096][512]
               float* __restrict__ outp,
               const float* __restrict__ xres,
               const float* __restrict__ pbias) {
  __shared__ __align__(16) unsigned short As[64*32];
  __shared__ __align__(16) unsigned short Bs[128*32];
  const int b   = blockIdx.z;
  const int n0  = blockIdx.x * 128;
  const int o0  = blockIdx.y * 64;
  const int tid = threadIdx.x;
  const int wave = tid >> 6, lane = tid & 63;
  const int wr = wave >> 1, wc = wave & 1;
  const int fm = lane & 15, fq = lane >> 4;
  const int srow = lane >> 2, scol = (lane & 3) * 8;

  const unsigned short* Ab = A + (size_t)o0 * 512;
  const unsigned short* Bb = Bt + ((size_t)b*4096 + n0) * 512;

  floatx4 acc[2][4];
  #pragma unroll
  for (int i = 0; i < 2; i++)
    #pragma unroll
    for (int j = 0; j < 4; j++) acc[i][j] = (floatx4){0.f,0.f,0.f,0.f};

  for (int k0 = 0; k0 < 512; k0 += 32) {
    __syncthreads();
    async16(Ab + (size_t)(wave*16 + srow)*512 + k0 + scol, &As[wave*512]);
    #pragma unroll
    for (int cc = 0; cc < 2; cc++) {
      int ch = wave*2 + cc;
      async16(Bb + (size_t)(ch*16 + srow)*512 + k0 + scol, &Bs[ch*512]);
    }
    __syncthreads();
    short8 af[2], bf[4];
    #pragma unroll
    for (int f = 0; f < 2; f++)
      af[f] = *(const short8*)&As[(wr*32 + f*16 + fm)*32 + fq*8];
    #pragma unroll
    for (int f = 0; f < 4; f++)
      bf[f] = *(const short8*)&Bs[(wc*64 + f*16 + fm)*32 + fq*8];
    #pragma unroll
    for (int fr = 0; fr < 2; fr++)
      #pragma unroll
      for (int fc = 0; fc < 4; fc++)
        acc[fr][fc] = __builtin_amdgcn_mfma_f32_16x16x32_bf16(af[fr], bf[fc], acc[fr][fc], 0, 0, 0);
  }

  #pragma unroll
  for (int fr = 0; fr < 2; fr++)
    #pragma unroll
    for (int fc = 0; fc < 4; fc++) {
      const int i = n0 + wc*64 + fc*16 + fm;
      #pragma unroll
      for (int r = 0; r < 4; r++) {
        const int o = o0 + wr*32 + fr*16 + fq*4 + r;
        const size_t idx = ((size_t)b*512 + o)*4096 + i;
        outp[idx] = xres[idx] + pbias[o] + acc[fr][fc][r];
      }
    }
}

// ---------------------------------------------------------------- attention
// 64 q-rows per WAVE (2 ih sub-tiles): K-frags and V-frags are i-independent,
// so one set of LDS frag reads feeds both ih sub-tiles (LDS/work halves vs R5).
// K+V double-buffered LDS via register prefetch; P stays in registers
// (S^T C-layout == PV A-layout per 8-j subtile); V j-interleaved for b128.
// Block = 4 waves = 256 q-rows. Grid (16, 16, [2 js]).
template <int SPLIT>
__global__ __launch_bounds__(256, 2)
void attn_kernel(const unsigned short* __restrict__ q_t,
                 const unsigned short* __restrict__ k_t,
                 const unsigned short* __restrict__ v_,
                 unsigned short* __restrict__ hout_t,
                 unsigned short* __restrict__ o_part,
                 float* __restrict__ l_part) {
  __shared__ __align__(16) unsigned short Ks[2][64*72];   // [j][k], +pad
  __shared__ __align__(16) unsigned short Vs[2][64*72];   // [d][j-interleaved], +pad

  const int bh  = blockIdx.x;
  const int q0  = blockIdx.y * 256;
  const int js  = SPLIT ? blockIdx.z : 0;
  const int nit = SPLIT ? 32 : 64;
  const int jbase = js * 2048;
  const int tid = threadIdx.x;
  const int wave = tid >> 6, lane = tid & 63;
  const int ln = lane & 31, h = lane >> 5;

  // Q B-frags (32x32x16): token i = q0 + wave*64 + ih*32 + ln
  short8 qf[2][4];
  #pragma unroll
  for (int ih = 0; ih < 2; ih++) {
    const unsigned short* qrow = q_t + ((size_t)bh*4096 + q0 + wave*64 + ih*32 + ln)*64;
    #pragma unroll
    for (int kc = 0; kc < 4; kc++)
      qf[ih][kc] = *(const short8*)(qrow + kc*16 + h*8);
  }

  const floatx16 z16 = {0.f,0.f,0.f,0.f,0.f,0.f,0.f,0.f,
                        0.f,0.f,0.f,0.f,0.f,0.f,0.f,0.f};
  floatx16 o_acc[2][2];   // [ih][dn]
  #pragma unroll
  for (int ih = 0; ih < 2; ih++) { o_acc[ih][0] = z16; o_acc[ih][1] = z16; }
  float l0 = 0.f, l1 = 0.f;   // per-lane denominators, token = lane ln (per ih)

  const int sr = tid >> 3;          // 0..31
  const int sc = (tid & 7) * 8;     // source 8-short chunk
  const int cch = tid & 7;          // chunk id within 64-j row
  const int vpos = ((cch >> 2) * 32) + ((cch & 3) * 4);
  const unsigned short* kbase = k_t + (size_t)bh*262144;
  const unsigned short* vbase = v_  + (size_t)bh*262144;

  // preload tile 0 into registers
  uint4 kr0 = *(const uint4*)&kbase[(size_t)(jbase + sr)*64 + sc];
  uint4 kr1 = *(const uint4*)&kbase[(size_t)(jbase + sr + 32)*64 + sc];
  uint4 vr0 = *(const uint4*)&vbase[(size_t)sr*4096 + jbase + sc];
  uint4 vr1 = *(const uint4*)&vbase[(size_t)(sr+32)*4096 + jbase + sc];

  for (int it = 0; it < nit; it++) {
    unsigned short* Kc = Ks[it & 1];
    unsigned short* Vc = Vs[it & 1];
    *(uint4*)&Kc[sr*72 + sc]      = kr0;
    *(uint4*)&Kc[(sr+32)*72 + sc] = kr1;
    *(uint2*)&Vc[sr*72 + vpos]           = *(const uint2*)&vr0;
    *(uint2*)&Vc[sr*72 + vpos + 16]      = *((const uint2*)&vr0 + 1);
    *(uint2*)&Vc[(sr+32)*72 + vpos]      = *(const uint2*)&vr1;
    *(uint2*)&Vc[(sr+32)*72 + vpos + 16] = *((const uint2*)&vr1 + 1);
    __syncthreads();

    // issue next tile's global loads (latency hidden behind compute)
    {
      const int jn = jbase + (((it + 1) & (nit - 1)) * 64);
      kr0 = *(const uint4*)&kbase[(size_t)(jn + sr)*64 + sc];
      kr1 = *(const uint4*)&kbase[(size_t)(jn + sr + 32)*64 + sc];
      vr0 = *(const uint4*)&vbase[(size_t)sr*4096 + jn + sc];
      vr1 = *(const uint4*)&vbase[(size_t)(sr+32)*4096 + jn + sc];
    }

    #pragma unroll
    for (int mj = 0; mj < 2; mj++) {
      // K/V frags once per mj, reused by both ih sub-tiles
      short8 kf[4];
      #pragma unroll
      for (int kc = 0; kc < 4; kc++)
        kf[kc] = *(const short8*)&Kc[(mj*32 + ln)*72 + kc*16 + h*8];
      short8 vv[2][2];   // [dn][t2]
      #pragma unroll
      for (int dn = 0; dn < 2; dn++)
        #pragma unroll
        for (int t2 = 0; t2 < 2; t2++)
          vv[dn][t2] = *(const short8*)&Vc[(dn*32 + ln)*72 + mj*32 + h*16 + t2*8];

      #pragma unroll
      for (int ih = 0; ih < 2; ih++) {
        // S^T = K Q^T
        floatx16 st = __builtin_amdgcn_mfma_f32_32x32x16_bf16(kf[0], qf[ih][0], z16, 0, 0, 0);
        #pragma unroll
        for (int kc = 1; kc < 4; kc++)
          st = __builtin_amdgcn_mfma_f32_32x32x16_bf16(kf[kc], qf[ih][kc], st, 0, 0, 0);

        // p = exp2(s'), accumulate l, pack to bf16 pairs
        unsigned pk[8];
        float lacc = 0.f;
        #pragma unroll
        for (int rp = 0; rp < 8; rp++) {
          float p0 = fast_exp2(st[2*rp]);
          float p1 = fast_exp2(st[2*rp + 1]);
          lacc += p0 + p1;
          pk[rp] = __builtin_amdgcn_perm(rbits(p1), rbits(p0), 0x07060302u);
        }
        if (ih) l1 += lacc; else l0 += lacc;

        // O += P V via 32x32x8 (V b128 covers 2 subtiles, interleaved layout)
        #pragma unroll
        for (int t2 = 0; t2 < 2; t2++) {
          union { unsigned u[2]; short4v s; } a0, a1;
          a0.u[0] = pk[4*t2];     a0.u[1] = pk[4*t2 + 1];
          a1.u[0] = pk[4*t2 + 2]; a1.u[1] = pk[4*t2 + 3];
          #pragma unroll
          for (int dn = 0; dn < 2; dn++) {
            short4v vlo = __builtin_shufflevector(vv[dn][t2], vv[dn][t2], 0, 1, 2, 3);
            short4v vhi = __builtin_shufflevector(vv[dn][t2], vv[dn][t2], 4, 5, 6, 7);
            o_acc[ih][dn] = __builtin_amdgcn_mfma_f32_32x32x8bf16_1k(a0.s, vlo, o_acc[ih][dn], 0, 0, 0);
            o_acc[ih][dn] = __builtin_amdgcn_mfma_f32_32x32x8bf16_1k(a1.s, vhi, o_acc[ih][dn], 0, 0, 0);
          }
        }
      }
    }
  }

  // column sums complete within lane pairs (h=0/1)
  l0 += __shfl_xor(l0, 32, 64);
  l1 += __shfl_xor(l1, 32, 64);

  if (SPLIT) {
    #pragma unroll
    for (int ih = 0; ih < 2; ih++) {
      unsigned short* op = o_part +
          (((size_t)(js*16 + bh)*4096 + q0 + wave*64 + ih*32) * 64);
      #pragma unroll
      for (int r = 0; r < 16; r++) {
        const int il = (r & 3) + 8*(r >> 2) + 4*h;   // token row within 32
        op[(size_t)il*64 + ln]      = f2bf(o_acc[ih][0][r]);
        op[(size_t)il*64 + 32 + ln] = f2bf(o_acc[ih][1][r]);
      }
    }
    if (lane < 32) {
      l_part[(size_t)(js*16 + bh)*4096 + q0 + wave*64 + lane]      = l0;
      l_part[(size_t)(js*16 + bh)*4096 + q0 + wave*64 + 32 + lane] = l1;
    }
  } else {
    const float linv0 = 1.f / l0;
    const float linv1 = 1.f / l1;
    const int bb = bh >> 3;
    const int cb = (bh & 7) * 64;
    #pragma unroll
    for (int ih = 0; ih < 2; ih++) {
      #pragma unroll
      for (int r = 0; r < 16; r++) {
        const int il = (r & 3) + 8*(r >> 2) + 4*h;
        const float inv = __shfl(ih ? linv1 : linv0, il, 64);
        const int i = q0 + wave*64 + ih*32 + il;
        unsigned short* dst = &hout_t[((size_t)bb*4096 + i)*512 + cb + ln];
        dst[0]  = f2bf(o_acc[ih][0][r] * inv);
        dst[32] = f2bf(o_acc[ih][1][r] * inv);
      }
    }
  }
}

// combine: hout = (O0+O1)/(l0+l1), bf16 token-major
__global__ void attn_combine(const unsigned short* __restrict__ o_part,
                             const float* __restrict__ l_part,
                             unsigned short* __restrict__ hout_t) {
  const int bh = blockIdx.x;
  const int i0 = blockIdx.y * 64;
  const int t  = threadIdx.x;
  const int d4 = (t & 15) * 4;
  const int il = t >> 4;
  const int bb = bh >> 3;
  const int cb = (bh & 7) * 64;
  const size_t JS = (size_t)16 * 4096 * 64;   // js stride in o_part
  #pragma unroll
  for (int p = 0; p < 4; p++) {
    const int i = i0 + p*16 + il;
    const size_t ob = ((size_t)bh*4096 + i)*64 + d4;
    uint2 a = *(const uint2*)&o_part[ob];
    uint2 b = *(const uint2*)&o_part[ob + JS];
    const size_t lb = (size_t)bh*4096 + i;
    const float inv = 1.f / (l_part[lb] + l_part[lb + 65536]);
    float o0 = (bf2f((unsigned short)(a.x & 0xffff)) + bf2f((unsigned short)(b.x & 0xffff))) * inv;
    float o1 = (bf2f((unsigned short)(a.x >> 16))    + bf2f((unsigned short)(b.x >> 16)))    * inv;
    float o2 = (bf2f((unsigned short)(a.y & 0xffff)) + bf2f((unsigned short)(b.y & 0xffff))) * inv;
    float o3 = (bf2f((unsigned short)(a.y >> 16))    + bf2f((unsigned short)(b.y >> 16)))    * inv;
    uint2 w;
    w.x = pack2(f2bf(o0), f2bf(o1));
    w.y = pack2(f2bf(o2), f2bf(o3));
    *(uint2*)&hout_t[((size_t)bb*4096 + i)*512 + cb + d4] = w;
  }
}

// ---------------------------------------------------------------- launcher
extern "C" void kernel_launch(void* const* d_in, const int* in_sizes, int n_in,
                              void* d_out, int out_size, void* d_ws, size_t ws_size,
                              hipStream_t stream) {
  (void)in_sizes; (void)n_in; (void)out_size;
  const float* x      = (const float*)d_in[0];
  const float* qkv_w  = (const float*)d_in[1];
  const float* proj_w = (const float*)d_in[2];
  const float* proj_b = (const float*)d_in[3];
  const float* gn_w   = (const float*)d_in[4];
  const float* gn_b   = (const float*)d_in[5];
  float* out = (float*)d_out;

  char* ws = (char*)d_ws;
  unsigned short* h_t   = (unsigned short*)(ws);                      // 8 MB, reused as hout_t
  unsigned short* q_t   = (unsigned short*)(ws + ((size_t)8  << 20));
  unsigned short* k_t   = (unsigned short*)(ws + ((size_t)16 << 20));
  unsigned short* v_    = (unsigned short*)(ws + ((size_t)24 << 20));
  unsigned short* wqkv  = (unsigned short*)(ws + ((size_t)32 << 20));
  unsigned short* wproj = (unsigned short*)(ws + ((size_t)34 << 20));
  float* stats          = (float*)(ws + ((size_t)35 << 20));
  unsigned short* o_part = (unsigned short*)(ws + ((size_t)36 << 20)); // 16 MB
  float* l_part          = (float*)(ws + ((size_t)52 << 20));          // 512 KB
  unsigned short* hout_t = h_t;

  const bool split = ws_size >= (((size_t)52 << 20) + ((size_t)1 << 19));

  setup_kernel<<<dim3(1088), dim3(256), 0, stream>>>(x, stats, qkv_w, wqkv, proj_w, wproj);
  gn_apply_t<<<dim3(64, 8, 2), dim3(256), 0, stream>>>(x, stats, gn_w, gn_b, h_t);
  qkv_gemm<<<dim3(32, 12, 2), dim3(256), 0, stream>>>(wqkv, h_t, q_t, k_t, v_);
  if (split) {
    attn_kernel<1><<<dim3(16, 16, 2), dim3(256), 0, stream>>>(q_t, k_t, v_, nullptr,
                                                              o_part, l_part);
    attn_combine<<<dim3(16, 64), dim3(256), 0, stream>>>(o_part, l_part, hout_t);
  } else {
    attn_kernel<0><<<dim3(16, 16), dim3(256), 0, stream>>>(q_t, k_t, v_, hout_t,
                                                           nullptr, nullptr);
  }
  proj_gemm<<<dim3(32, 8, 2), dim3(256), 0, stream>>>(wproj, hout_t, out, x, proj_b);
}